// Round 12
// baseline (279.055 us; speedup 1.0000x reference)
//
#include <hip/hip_runtime.h>
#include <hip/hip_bf16.h>
#include <math.h>

#define D 64

typedef __attribute__((ext_vector_type(8))) short bf16x8;
typedef __attribute__((ext_vector_type(8))) _Float16 f16x8;
typedef __attribute__((ext_vector_type(8))) unsigned short u16x8;
typedef __attribute__((ext_vector_type(4))) float f32x4;
typedef unsigned short u16;
typedef unsigned long long u64;

__device__ __forceinline__ float gelu_erf(float x) {
    return 0.5f * x * (1.0f + erff(x * 0.70710678118654752f));
}
__device__ __forceinline__ float gelu_tanh(float x) {
    float u = x * fmaf(x * x, 0.035677408136f, 0.7978845608028654f);
    float e = __expf(2.0f * u);
    float th = 1.0f - 2.0f / (e + 1.0f);
    return 0.5f * x * (1.0f + th);
}
__device__ __forceinline__ u16 f2bf(float v) {
    __hip_bfloat16 h = __float2bfloat16(v);
    return *(u16*)&h;
}
__device__ __forceinline__ float bf2f(u16 v) {
    return __uint_as_float(((unsigned int)v) << 16);
}
__device__ __forceinline__ u16 f2h(float v) {
    _Float16 h = (_Float16)v;
    return __builtin_bit_cast(u16, h);
}
__device__ __forceinline__ void atomic_pk_add_f16(u16* addr, float lo, float hi) {
    unsigned int p = (unsigned int)f2h(lo) | ((unsigned int)f2h(hi) << 16);
    asm volatile("global_atomic_pk_add_f16 %0, %1, off sc1" :: "v"(addr), "v"(p));
}
// pos p holds dim pi(p) = (p&3)*16 + (p>>2)
__device__ __forceinline__ int pi_perm(int p) { return ((p & 3) << 4) | (p >> 2); }

// ---- K1: weight B-fragment packing (blocks 0..11) + key histogram (rest)
// key = 2*dst + (same ? 0 : 1)
__global__ __launch_bounds__(256) void prep_hist(
    const float* __restrict__ Wt, const float* __restrict__ Wq,
    const float* __restrict__ Wks, const float* __restrict__ Wkd,
    const float* __restrict__ Wvs, const float* __restrict__ Wvd,
    u16* __restrict__ WtB, u16* __restrict__ WqB,
    u16* __restrict__ WksB, u16* __restrict__ WkdB,
    u16* __restrict__ WvsB, u16* __restrict__ WvdB,
    const int* __restrict__ ei, const float* __restrict__ esame,
    int* __restrict__ cnt, int E)
{
    if (blockIdx.x < 12) {
        int task = blockIdx.x * 4 + (threadIdx.x >> 6);  // 0..47
        int lane = threadIdx.x & 63;
        int wsel = task >> 3, f = task & 7;
        int c = lane & 15, quad = lane >> 4;
        int nt = f >> 1, kk = f & 1;
        for (int j = 0; j < 8; ++j) {
            int n = nt * 16 + c, k = kk * 32 + quad * 8 + j;
            float v; u16* dp; bool h16 = false;
            switch (wsel) {
                case 0: v = Wt[n * 65 + k];  dp = WtB;  break;
                case 1: v = Wq[n * 64 + k];  dp = WqB;  break;
                case 2: v = Wks[k * 64 + n]; dp = WksB; break;
                case 3: v = Wkd[k * 64 + n]; dp = WkdB; break;
                case 4: v = Wvs[n * 64 + pi_perm(k)]; dp = WvsB; h16 = true; break;
                default: v = Wvd[n * 64 + pi_perm(k)]; dp = WvdB; h16 = true; break;
            }
            dp[(f * 64 + lane) * 8 + j] = h16 ? f2h(v) : f2bf(v);
        }
    } else {
        int gid = (blockIdx.x - 12) * 256 + threadIdx.x;
        int stride = (gridDim.x - 12) * 256;
        for (int e = gid; e < E; e += stride) {
            int key = 2 * ei[E + e] + (esame[e] > 0.5f ? 0 : 1);
            atomicAdd(&cnt[key], 1);
        }
    }
}

// ---- hierarchical scan (2 kernels): A) per-block sums, C) local scan + self-computed offset
#define SCAN_CHUNK 2048

__global__ __launch_bounds__(256) void scan_phaseA(const int* __restrict__ cnt,
                                                   int* __restrict__ bsum, int M)
{
    int base = blockIdx.x * SCAN_CHUNK;
    int s = 0;
    for (int i = threadIdx.x; i < SCAN_CHUNK; i += 256) {
        int idx = base + i;
        s += (idx < M) ? cnt[idx] : 0;
    }
    #pragma unroll
    for (int o = 32; o; o >>= 1) s += __shfl_xor(s, o);
    __shared__ int red[4];
    if ((threadIdx.x & 63) == 0) red[threadIdx.x >> 6] = s;
    __syncthreads();
    if (threadIdx.x == 0) bsum[blockIdx.x] = red[0] + red[1] + red[2] + red[3];
}

__global__ __launch_bounds__(256) void scan_phaseC(const int* __restrict__ cnt,
                                                   const int* __restrict__ bsum,
                                                   int* __restrict__ cursor, int M, int nb)
{
    // block offset = sum of bsum[k] for k < blockIdx.x (nb <= 256)
    __shared__ int bred[4];
    __shared__ int boff_s;
    {
        int t = threadIdx.x;
        int v = (t < nb && t < blockIdx.x) ? bsum[t] : 0;
        #pragma unroll
        for (int o = 32; o; o >>= 1) v += __shfl_xor(v, o);
        if ((t & 63) == 0) bred[t >> 6] = v;
        __syncthreads();
        if (t == 0) boff_s = bred[0] + bred[1] + bred[2] + bred[3];
        __syncthreads();
    }
    const int boff = boff_s;

    int base = blockIdx.x * SCAN_CHUNK;
    int i0 = base + threadIdx.x * 8;
    int vals[8];
    int tsum = 0;
    #pragma unroll
    for (int j = 0; j < 8; ++j) {
        int idx = i0 + j;
        vals[j] = (idx < M) ? cnt[idx] : 0;
        tsum += vals[j];
    }
    int lane = threadIdx.x & 63;
    int w = threadIdx.x >> 6;
    int inc = tsum;
    #pragma unroll
    for (int o = 1; o < 64; o <<= 1) {
        int v = __shfl_up(inc, o);
        if (lane >= o) inc += v;
    }
    __shared__ int wsum[4];
    if (lane == 63) wsum[w] = inc;
    __syncthreads();
    int woff = 0;
    #pragma unroll
    for (int k = 0; k < 4; ++k) woff += (k < w) ? wsum[k] : 0;
    int excl = woff + (inc - tsum) + boff;
    #pragma unroll
    for (int j = 0; j < 8; ++j) {
        int idx = i0 + j;
        if (idx < M) cursor[idx] = excl;
        excl += vals[j];
    }
}

// ---- K3 (fat): [0,GS) scatter (1 edge/thread, packed 8-B record) |
//                [GS,GS+GZ) zero A+den | [GS+GZ,...) fused LN + q-chain
// record: bits[15:0]=src, [32:16]=key, [63:48]=t*65535 (N<=65536 assumed)
__global__ __launch_bounds__(256) void scatter_qgemm(
    const int* __restrict__ ei, const float* __restrict__ et,
    const float* __restrict__ esame, int* __restrict__ cursor,
    u64* __restrict__ ev, int E, int GS, int GZ,
    u16* __restrict__ Azero, long zvecs,
    const float* __restrict__ x, const float* __restrict__ gamma, const float* __restrict__ beta,
    const u16* __restrict__ WqB, const u16* __restrict__ WksB, const u16* __restrict__ WkdB,
    const float* __restrict__ bq, const float* __restrict__ bks, const float* __restrict__ bkd,
    u16* __restrict__ xnb, u16* __restrict__ qk2, float* __restrict__ bq2, int N)
{
    __shared__ u16 qtile[4][16 * 64];
    __shared__ u16 stile[4][32 * 64];

    if (blockIdx.x < GS) {
        // ---------- scatter: one edge per thread ----------
        int e = blockIdx.x * 256 + threadIdx.x;
        if (e < E) {
            int key = 2 * ei[E + e] + (esame[e] > 0.5f ? 0 : 1);
            int pos = atomicAdd(&cursor[key], 1);
            unsigned int tq = (unsigned int)rintf(et[e] * 65535.0f);
            u64 w = (u64)(unsigned int)ei[e] | ((u64)(unsigned int)key << 16) | ((u64)tq << 48);
            ev[pos] = w;
        }
        return;
    }
    if (blockIdx.x < GS + GZ) {
        // ---------- zero A + den (contiguous region, 16-B vector stores) ----------
        u16x8 z = {0, 0, 0, 0, 0, 0, 0, 0};
        u16x8* p = (u16x8*)Azero;
        long stride = (long)GZ * 256;
        for (long i = (long)(blockIdx.x - GS) * 256 + threadIdx.x; i < zvecs; i += stride)
            p[i] = z;
        return;
    }

    // ---------- qgemm ----------
    const int lane = threadIdx.x & 63;
    const int c = lane & 15, quad = lane >> 4;
    const int w = threadIdx.x >> 6;
    const int wave = (blockIdx.x - GS - GZ) * 4 + w;
    const int n0r = wave * 16;
    const bool active = n0r < N;
    const int n0 = active ? n0r : 0;
    const int rowA = (n0 + c < N) ? n0 + c : N - 1;

    // fused LayerNorm in A-fragment layout
    const float* xrow = x + (long)rowA * D;
    f32x4 xa = *(const f32x4*)(xrow + quad * 8);
    f32x4 xb = *(const f32x4*)(xrow + quad * 8 + 4);
    f32x4 xc = *(const f32x4*)(xrow + 32 + quad * 8);
    f32x4 xd = *(const f32x4*)(xrow + 32 + quad * 8 + 4);
    float s = 0.f, s2 = 0.f;
    #pragma unroll
    for (int j = 0; j < 4; ++j) {
        s += xa[j] + xb[j] + xc[j] + xd[j];
        s2 += xa[j] * xa[j] + xb[j] * xb[j] + xc[j] * xc[j] + xd[j] * xd[j];
    }
    s += __shfl_xor(s, 16);  s += __shfl_xor(s, 32);
    s2 += __shfl_xor(s2, 16); s2 += __shfl_xor(s2, 32);
    float mu = s * (1.0f / 64.0f);
    float var = s2 * (1.0f / 64.0f) - mu * mu;
    float rinv = rsqrtf(var + 1e-5f);
    f32x4 ga = *(const f32x4*)(gamma + quad * 8);
    f32x4 gb = *(const f32x4*)(gamma + quad * 8 + 4);
    f32x4 gc = *(const f32x4*)(gamma + 32 + quad * 8);
    f32x4 gd = *(const f32x4*)(gamma + 32 + quad * 8 + 4);
    f32x4 ba = *(const f32x4*)(beta + quad * 8);
    f32x4 bb = *(const f32x4*)(beta + quad * 8 + 4);
    f32x4 bc = *(const f32x4*)(beta + 32 + quad * 8);
    f32x4 bd = *(const f32x4*)(beta + 32 + quad * 8 + 4);
    bf16x8 a0, a1;
    #pragma unroll
    for (int j = 0; j < 4; ++j) {
        a0[j]     = (short)f2bf(fmaf((xa[j] - mu) * rinv, ga[j], ba[j]));
        a0[4 + j] = (short)f2bf(fmaf((xb[j] - mu) * rinv, gb[j], bb[j]));
        a1[j]     = (short)f2bf(fmaf((xc[j] - mu) * rinv, gc[j], bc[j]));
        a1[4 + j] = (short)f2bf(fmaf((xd[j] - mu) * rinv, gd[j], bd[j]));
    }
    *(bf16x8*)(xnb + (long)rowA * D + quad * 8) = a0;
    *(bf16x8*)(xnb + (long)rowA * D + 32 + quad * 8) = a1;

    float bqc[4], bksc[4], bkdc[4];
    #pragma unroll
    for (int t = 0; t < 4; ++t) {
        bqc[t] = bq[t * 16 + c]; bksc[t] = bks[t * 16 + c]; bkdc[t] = bkd[t * 16 + c];
    }

    // GEMM1: q
    f32x4 accq[4];
    #pragma unroll
    for (int t = 0; t < 4; ++t) {
        bf16x8 b0 = *(const bf16x8*)(WqB + ((t * 2 + 0) * 64 + lane) * 8);
        bf16x8 b1 = *(const bf16x8*)(WqB + ((t * 2 + 1) * 64 + lane) * 8);
        f32x4 z = {0.f, 0.f, 0.f, 0.f};
        z = __builtin_amdgcn_mfma_f32_16x16x32_bf16(a0, b0, z, 0, 0, 0);
        z = __builtin_amdgcn_mfma_f32_16x16x32_bf16(a1, b1, z, 0, 0, 0);
        accq[t] = z;
    }
    #pragma unroll
    for (int r = 0; r < 4; ++r) {
        float qv[4], ss = 0.f, sd = 0.f;
        #pragma unroll
        for (int t = 0; t < 4; ++t) {
            qv[t] = accq[t][r] + bqc[t];
            ss = fmaf(qv[t], bksc[t], ss);
            sd = fmaf(qv[t], bkdc[t], sd);
        }
        #pragma unroll
        for (int o = 1; o < 16; o <<= 1) { ss += __shfl_xor(ss, o); sd += __shfl_xor(sd, o); }
        int nrow = n0 + quad * 4 + r;
        if (active && c == 0 && nrow < N)
            *(float2*)(bq2 + 2 * nrow) = make_float2(ss, sd);
        #pragma unroll
        for (int t = 0; t < 4; ++t)
            qtile[w][(quad * 4 + r) * 64 + t * 16 + c] = f2bf(qv[t]);
    }
    __syncthreads();

    // GEMM2: qks/qkd -> stile rows (2m, 2m+1), pi-permuted positions
    const u16* qrow = &qtile[w][c * 64 + quad * 8];
    bf16x8 q0 = *(const bf16x8*)(qrow);
    bf16x8 q1 = *(const bf16x8*)(qrow + 32);
    #pragma unroll
    for (int t = 0; t < 4; ++t) {
        bf16x8 bs0 = *(const bf16x8*)(WksB + ((t * 2 + 0) * 64 + lane) * 8);
        bf16x8 bs1 = *(const bf16x8*)(WksB + ((t * 2 + 1) * 64 + lane) * 8);
        bf16x8 bd0 = *(const bf16x8*)(WkdB + ((t * 2 + 0) * 64 + lane) * 8);
        bf16x8 bd1 = *(const bf16x8*)(WkdB + ((t * 2 + 1) * 64 + lane) * 8);
        f32x4 zs = {0.f, 0.f, 0.f, 0.f}, zd = {0.f, 0.f, 0.f, 0.f};
        zs = __builtin_amdgcn_mfma_f32_16x16x32_bf16(q0, bs0, zs, 0, 0, 0);
        zs = __builtin_amdgcn_mfma_f32_16x16x32_bf16(q1, bs1, zs, 0, 0, 0);
        zd = __builtin_amdgcn_mfma_f32_16x16x32_bf16(q0, bd0, zd, 0, 0, 0);
        zd = __builtin_amdgcn_mfma_f32_16x16x32_bf16(q1, bd1, zd, 0, 0, 0);
        #pragma unroll
        for (int r = 0; r < 4; ++r) {
            int m = quad * 4 + r;
            stile[w][(2 * m + 0) * 64 + c * 4 + t] = f2bf(zs[r]);
            stile[w][(2 * m + 1) * 64 + c * 4 + t] = f2bf(zd[r]);
        }
    }
    __syncthreads();
    if (active) {
        int nrows = min(16, N - n0);
        const u16x8* sp = (const u16x8*)&stile[w][0];
        u16x8* dp = (u16x8*)(qk2 + (long)(2 * n0) * D);
        int cnt8 = nrows * 16;
        for (int j = lane; j < cnt8; j += 64) dp[j] = sp[j];
    }
}

// ---- K4: edge pass over key-sorted packed records (run-aggregation in registers)
__global__ __launch_bounds__(256) void edge_pass(
    const u64* __restrict__ ev,
    const u16* __restrict__ xnb, const u16* __restrict__ WtB,
    const float* __restrict__ Wt, const float* __restrict__ bt,
    const u16* __restrict__ qk2, const float* __restrict__ bq2,
    u16* __restrict__ A, float* __restrict__ den, int E, int chunk)
{
    const int lane = threadIdx.x & 63;
    const int c = lane & 15, quad = lane >> 4;
    const int wave = blockIdx.x * 4 + (threadIdx.x >> 6);
    const long base = (long)wave * chunk;
    if (base >= E) return;
    const long end = (base + chunk < (long)E) ? base + chunk : (long)E;
    const int qchunk = chunk >> 2;

    bf16x8 bfrag[8];
    #pragma unroll
    for (int f = 0; f < 8; ++f)
        bfrag[f] = *(const bf16x8*)(WtB + (f * 64 + lane) * 8);

    float btc[4], w64c[4], dva[4];
    #pragma unroll
    for (int t = 0; t < 4; ++t) {
        int dim = t * 16 + c;
        btc[t] = bt[dim];
        w64c[t] = Wt[dim * 65 + 64];
        dva[t] = 200.0f * expf(-9.210340371976184f * (float)(2 * (dim >> 1)) * (1.0f / 64.0f));
    }
    const float phoff = (c & 1) ? 1.5707963267948966f : 0.0f;

    int cur_key = -1;
    float racc0 = 0.f, racc1 = 0.f, racc2 = 0.f, racc3 = 0.f, rden = 0.f;
    ushort4 q4 = {0, 0, 0, 0};
    float bqv = 0.f;

    const long rowbase = base + (long)(c >> 2) * qchunk + (c & 3);

    for (int i = 0; i < qchunk; i += 4) {
        long eidx = rowbase + i;
        long ec = eidx < end ? eidx : end - 1;
        u64 wrec = ev[ec];
        int srcL = (int)(wrec & 0xFFFF);
        int keyL = (int)((wrec >> 16) & 0x1FFFF);
        float tL = (float)(unsigned int)(wrec >> 48) * (1.0f / 65535.0f);

        const u16* ar = xnb + (long)srcL * D + quad * 8;
        bf16x8 a0 = *(const bf16x8*)(ar);
        bf16x8 a1 = *(const bf16x8*)(ar + 32);

        f32x4 acc[4];
        #pragma unroll
        for (int t = 0; t < 4; ++t) {
            f32x4 z = {0.f, 0.f, 0.f, 0.f};
            z = __builtin_amdgcn_mfma_f32_16x16x32_bf16(a0, bfrag[t * 2 + 0], z, 0, 0, 0);
            z = __builtin_amdgcn_mfma_f32_16x16x32_bf16(a1, bfrag[t * 2 + 1], z, 0, 0, 0);
            acc[t] = z;
        }

        #pragma unroll
        for (int r = 0; r < 4; ++r) {
            int m = quad * 4 + r;
            int keym = __shfl(keyL, m);
            float tm = __shfl(tL, m);
            long eglob = base + (long)quad * qchunk + i + r;
            bool vm = eglob < end;

            float xtv[4];
            #pragma unroll
            for (int t = 0; t < 4; ++t) {
                float v = gelu_tanh(acc[t][r] + fmaf(tm, w64c[t], btc[t]));
                v += __sinf(fmaf(tm, dva[t], phoff));
                xtv[t] = v;
            }

            if (keym != cur_key) {
                if (cur_key >= 0) {
                    u16* ap = A + (long)cur_key * D + c * 4;
                    atomic_pk_add_f16(ap, racc0, racc1);
                    atomic_pk_add_f16(ap + 2, racc2, racc3);
                    if (c == 0) atomicAdd(&den[cur_key], rden);
                }
                cur_key = keym;
                q4 = *(const ushort4*)(qk2 + (long)keym * D + c * 4);
                bqv = bq2[keym];
                racc0 = racc1 = racc2 = racc3 = 0.f;
                rden = 0.f;
            }

            float p = xtv[0] * bf2f(q4.x);
            p = fmaf(xtv[1], bf2f(q4.y), p);
            p = fmaf(xtv[2], bf2f(q4.z), p);
            p = fmaf(xtv[3], bf2f(q4.w), p);
            #pragma unroll
            for (int o = 1; o < 16; o <<= 1) p += __shfl_xor(p, o);
            float ex = vm ? __expf((p + bqv) * 0.125f) : 0.0f;

            racc0 = fmaf(ex, xtv[0], racc0);
            racc1 = fmaf(ex, xtv[1], racc1);
            racc2 = fmaf(ex, xtv[2], racc2);
            racc3 = fmaf(ex, xtv[3], racc3);
            if (c == 0) rden += ex;
        }
    }

    if (cur_key >= 0) {
        u16* ap = A + (long)cur_key * D + c * 4;
        atomic_pk_add_f16(ap, racc0, racc1);
        atomic_pk_add_f16(ap + 2, racc2, racc3);
        if (c == 0) atomicAdd(&den[cur_key], rden);
    }
}

// ---- K5: node post (MFMA value-GEMM + output)
__global__ __launch_bounds__(256) void vgemm(
    const float* __restrict__ x, const u16* __restrict__ A, const float* __restrict__ den,
    const u16* __restrict__ WvsB, const u16* __restrict__ WvdB,
    const float* __restrict__ bvs, const float* __restrict__ bvd,
    float* __restrict__ out, int N)
{
    const int lane = threadIdx.x & 63;
    const int c = lane & 15, quad = lane >> 4;
    const int wave = blockIdx.x * 4 + (threadIdx.x >> 6);
    const int n0 = wave * 16;
    if (n0 >= N) return;
    const int rowA = (n0 + c < N) ? n0 + c : N - 1;

    float bvsc[4], bvdc[4];
    #pragma unroll
    for (int t = 0; t < 4; ++t) { bvsc[t] = bvs[t * 16 + c]; bvdc[t] = bvd[t * 16 + c]; }

    const u16* srow = A + (long)(2 * rowA) * D + quad * 8;
    const u16* drow = A + (long)(2 * rowA + 1) * D + quad * 8;
    f16x8 s0 = *(const f16x8*)(srow);
    f16x8 s1 = *(const f16x8*)(srow + 32);
    f16x8 d0 = *(const f16x8*)(drow);
    f16x8 d1 = *(const f16x8*)(drow + 32);

    f32x4 oacc[4];
    #pragma unroll
    for (int t = 0; t < 4; ++t) {
        f16x8 bs0 = *(const f16x8*)(WvsB + ((t * 2 + 0) * 64 + lane) * 8);
        f16x8 bs1 = *(const f16x8*)(WvsB + ((t * 2 + 1) * 64 + lane) * 8);
        f16x8 bd0 = *(const f16x8*)(WvdB + ((t * 2 + 0) * 64 + lane) * 8);
        f16x8 bd1 = *(const f16x8*)(WvdB + ((t * 2 + 1) * 64 + lane) * 8);
        f32x4 z = {0.f, 0.f, 0.f, 0.f};
        z = __builtin_amdgcn_mfma_f32_16x16x32_f16(s0, bs0, z, 0, 0, 0);
        z = __builtin_amdgcn_mfma_f32_16x16x32_f16(s1, bs1, z, 0, 0, 0);
        z = __builtin_amdgcn_mfma_f32_16x16x32_f16(d0, bd0, z, 0, 0, 0);
        z = __builtin_amdgcn_mfma_f32_16x16x32_f16(d1, bd1, z, 0, 0, 0);
        oacc[t] = z;
    }

    #pragma unroll
    for (int r = 0; r < 4; ++r) {
        int n = n0 + quad * 4 + r;
        if (n >= N) continue;
        float ds = den[2 * n], dd = den[2 * n + 1];
        float inv = 1.0f / (ds + dd + 1e-16f);
        float fs = ds * inv, fd = dd * inv;
        #pragma unroll
        for (int t = 0; t < 4; ++t) {
            long idx = (long)n * D + t * 16 + c;
            float o = fmaf(oacc[t][r], inv, fmaf(fs, bvsc[t], fd * bvdc[t]));
            out[idx] = x[idx] + gelu_erf(o);
        }
    }
}

extern "C" void kernel_launch(void* const* d_in, const int* in_sizes, int n_in,
                              void* d_out, int out_size, void* d_ws, size_t ws_size,
                              hipStream_t stream) {
    const float* x        = (const float*)d_in[0];
    const int*   ei       = (const int*)d_in[1];
    const float* et       = (const float*)d_in[2];
    const float* esame    = (const float*)d_in[4];
    const float* ln_gamma = (const float*)d_in[5];
    const float* ln_beta  = (const float*)d_in[6];
    const float* Wt  = (const float*)d_in[7];
    const float* bt  = (const float*)d_in[8];
    const float* Wq  = (const float*)d_in[9];
    const float* bq  = (const float*)d_in[10];
    const float* Wks = (const float*)d_in[11];
    const float* bks = (const float*)d_in[12];
    const float* Wkd = (const float*)d_in[13];
    const float* bkd = (const float*)d_in[14];
    const float* Wvs = (const float*)d_in[15];
    const float* bvs = (const float*)d_in[16];
    const float* Wvd = (const float*)d_in[17];
    const float* bvd = (const float*)d_in[18];
    float* out = (float*)d_out;

    const int N = in_sizes[0] / D;   // 50000 (packed record assumes N <= 65536)
    const int E = in_sizes[2];       // 800000
    const int M = 2 * N;             // key space

    u16* A      = (u16*)d_ws;                    // M*64 f16 (A then den contiguous)
    float* den  = (float*)(A + (long)M * D);
    int* cnt    = (int*)(den + M);
    int* cursor = cnt + M;
    float* bq2  = (float*)(cursor + M);
    u64* ev     = (u64*)(bq2 + M);               // E packed records
    int* bsum   = (int*)(ev + E);                // scan block sums (<=256)
    u16* xnb    = (u16*)(bsum + 256);
    u16* qk2    = xnb + (long)N * D;
    u16* WtB    = qk2 + (long)M * D;
    u16* WqB    = WtB + 4096;
    u16* WksB   = WqB + 4096;
    u16* WkdB   = WksB + 4096;
    u16* WvsB   = WkdB + 4096;
    u16* WvdB   = WvsB + 4096;

    // zero only cnt (A+den zeroed inside scatter_qgemm)
    hipMemsetAsync(cnt, 0, (size_t)M * sizeof(int), stream);

    prep_hist<<<12 + 976, 256, 0, stream>>>(Wt, Wq, Wks, Wkd, Wvs, Wvd,
                                            WtB, WqB, WksB, WkdB, WvsB, WvdB,
                                            ei, esame, cnt, E);
    const int nbScan = (M + SCAN_CHUNK - 1) / SCAN_CHUNK;   // 49 @ M=100k
    scan_phaseA<<<nbScan, 256, 0, stream>>>(cnt, bsum, M);
    scan_phaseC<<<nbScan, 256, 0, stream>>>(cnt, bsum, cursor, M, nbScan);

    const int GS = (E + 255) / 256;              // scatter blocks (3125)
    const int GZ = 128;                          // zero blocks
    const int GQ = ((N + 15) / 16 + 3) / 4;      // qgemm blocks (782)
    const long zvecs = ((long)M * D * 2 + (long)M * 4) / 16;  // A+den in 16-B units
    scatter_qgemm<<<GS + GZ + GQ, 256, 0, stream>>>(
        ei, et, esame, cursor, ev, E, GS, GZ, A, zvecs,
        x, ln_gamma, ln_beta, WqB, WksB, WkdB, bq, bks, bkd,
        xnb, qk2, bq2, N);

    const int nwaves = 2048 * 4;
    const int chunk = ((E + nwaves * 16 - 1) / (nwaves * 16)) * 16;  // 112 @ E=800k
    edge_pass<<<2048, 256, 0, stream>>>(ev, xnb, WtB, Wt, bt,
                                        qk2, bq2, A, den, E, chunk);
    vgemm<<<GQ, 256, 0, stream>>>(x, A, den, WvsB, WvdB, bvs, bvd, out, N);
}